// Round 4
// baseline (177.446 us; speedup 1.0000x reference)
//
#include <hip/hip_runtime.h>
#include <hip/hip_bf16.h>

#define NHEADS 16
#define HDIM   64
#define HID    1024
#define BB     4
#define SS     4096
#define MM     (BB*SS)      // 16384 rows
#define KK     HID          // 1024
#define NN     (2*HID)      // 2048 cols (Q | K)

using short8 = __attribute__((ext_vector_type(8))) short;
using f32x4  = __attribute__((ext_vector_type(4))) float;

__device__ __forceinline__ float bf2f(ushort u) {
  return __uint_as_float(((unsigned)u) << 16);
}
__device__ __forceinline__ ushort f2bf(float f) {
  unsigned u = __float_as_uint(f);
  unsigned r = (u + 0x7fffu + ((u >> 16) & 1u)) >> 16;  // RNE
  return (ushort)r;
}

__device__ __forceinline__ void gload16(const void* g, void* l) {
  __builtin_amdgcn_global_load_lds(
      (const __attribute__((address_space(1))) void*)g,
      (__attribute__((address_space(3))) void*)l, 16, 0, 0);
}

// ---------------------------------------------------------------- cast hs->bf16
__global__ __launch_bounds__(256) void cast_hs_k(const float* __restrict__ in,
                                                 ushort* __restrict__ out) {
  size_t i = ((size_t)blockIdx.x * 256 + threadIdx.x) * 8;
  float4 a = *(const float4*)(in + i);
  float4 b = *(const float4*)(in + i + 4);
  ushort r[8];
  r[0]=f2bf(a.x); r[1]=f2bf(a.y); r[2]=f2bf(a.z); r[3]=f2bf(a.w);
  r[4]=f2bf(b.x); r[5]=f2bf(b.y); r[6]=f2bf(b.z); r[7]=f2bf(b.w);
  *(uint4*)(out + i) = *(const uint4*)r;
}

// ------------------------------------------- W (K,N) -> Bt (N,K) bf16, Wq|Wkv fused
__global__ __launch_bounds__(256) void wcast_k(const float* __restrict__ Wq,
                                               const float* __restrict__ Wkv,
                                               ushort* __restrict__ Bt) {
  __shared__ float tile[32][33];
  int k0 = blockIdx.x * 32, n0 = blockIdx.y * 32;
  int tx = threadIdx.x, ty = threadIdx.y;
  const float* src = (n0 < HID) ? Wq : Wkv;
  int nc = (n0 < HID) ? n0 : n0 - HID;
#pragma unroll
  for (int j = 0; j < 4; ++j)
    tile[ty + 8*j][tx] = src[(size_t)(k0 + ty + 8*j) * HID + nc + tx];
  __syncthreads();
#pragma unroll
  for (int j = 0; j < 4; ++j)
    Bt[(size_t)(n0 + ty + 8*j) * KK + k0 + tx] = f2bf(tile[tx][ty + 8*j]);
}

// ---------------------------------------------------------------- fused QK GEMM
// 256x256 tile, BK=64, 8 waves (2Mx4N), 512 threads, 128KB LDS double-buffer.
// 8-phase schedule with K-SPLIT staging units (16KB = 256 rows x 32 cols):
// every staged slice has 4 phases issue-to-wait distance; vmcnt(8) at even
// tails never force-retires a fresh load. Chunk swizzle hi^((row>>1)&3) on
// 64B rows (2-way alias only = free); inverse involution on global source.
// Swapped-operand MFMA -> lane holds 4 consecutive C cols -> direct 8B stores.
// LDS byte map: A0K0=0 A0K1=16384 B0K0=32768 B0K1=49152
//               A1K0=65536 A1K1=81920 B1K0=98304 B1K1=114688
__global__ __launch_bounds__(512, 2) void gemm_k(const ushort* __restrict__ A,
                                                 const ushort* __restrict__ Bt,
                                                 const float* __restrict__ bq,
                                                 const float* __restrict__ bkv,
                                                 ushort* __restrict__ C) {
  extern __shared__ char lds_c[];
  const int tid = threadIdx.x;
  const int bid = blockIdx.x;
  const int wg = (bid & 7) * 64 + (bid >> 3);   // XCD swizzle (512 % 8 == 0)
  const int tm = wg >> 3, tn = wg & 7;
  const int w = tid >> 6, lane = tid & 63;
  const int wr = w >> 2, wc = w & 3;
  const int lr = lane & 15, hi = lane >> 4;

  const ushort* Ab = A  + (size_t)tm * 256 * KK;
  const ushort* Bb = Bt + (size_t)tn * 256 * KK;

  // staging: slice = 256 rows x 32 cols; thread t -> row t>>2 (+128 for j=1),
  // LDS chunk t&3; global chunk = (t&3) ^ ((t>>3)&3)  (involution pre-swizzle)
  const int d0 = tid * 16;                 // LDS byte offset, j=0
  const int gch = (tid & 3) ^ ((tid >> 3) & 3);
  const size_t soff0 = (size_t)(tid >> 2) * KK + gch * 8;
  const size_t soff1 = soff0 + (size_t)128 * KK;

  // fragment-read swizzle: chunk' = hi ^ ((row>>1)&3); (row>>1)&3 == (lr>>1)&3
  const int swz = (hi ^ ((lr >> 1) & 3)) << 4;
  const int arow = (wr * 128 + lr) * 64 + swz;   // + MH*4096 + m*1024
  const int brow = (wc * 64 + lr) * 64 + swz;    // + n*1024

  f32x4 acc[8][4];
#pragma unroll
  for (int M = 0; M < 8; ++M)
#pragma unroll
    for (int n = 0; n < 4; ++n) acc[M][n] = (f32x4){0.f, 0.f, 0.f, 0.f};
  short8 bfrag[4];

#define STG2(PANEL, KOFF)                                                       \
  /* dst patched by caller via DSTB */                                          \
  do {} while (0)

#define STG(PANEL, KOFF, DSTB)                                                  \
  {                                                                             \
    const ushort* g_ = (PANEL) + (KOFF);                                        \
    gload16(g_ + soff0, lds_c + (DSTB) + d0);                                   \
    gload16(g_ + soff1, lds_c + (DSTB) + 8192 + d0);                            \
  }

#define LOADB(BBASE)                                                            \
  _Pragma("unroll") for (int n = 0; n < 4; ++n)                                 \
    bfrag[n] = *(const short8*)(lds_c + (BBASE) + n * 1024 + brow);

#define WAITV(N)                                                                \
  { asm volatile("s_waitcnt vmcnt(" #N ")" ::: "memory");                       \
    __builtin_amdgcn_sched_barrier(0); }

#define PH(ABASE, MH, STAGE_CODE, TAIL_CODE)                                    \
  {                                                                             \
    short8 afrag[4];                                                            \
    _Pragma("unroll") for (int m = 0; m < 4; ++m)                               \
      afrag[m] = *(const short8*)(lds_c + (ABASE) + (MH) * 4096 +               \
                                  m * 1024 + arow);                             \
    STAGE_CODE;                                                                 \
    __builtin_amdgcn_s_barrier();                                               \
    asm volatile("" ::: "memory");                                              \
    __builtin_amdgcn_s_setprio(1);                                              \
    _Pragma("unroll") for (int m = 0; m < 4; ++m)                               \
      _Pragma("unroll") for (int n = 0; n < 4; ++n)                             \
        acc[(MH) * 4 + m][n] = __builtin_amdgcn_mfma_f32_16x16x32_bf16(         \
            bfrag[n], afrag[m], acc[(MH) * 4 + m][n], 0, 0, 0);                 \
    __builtin_amdgcn_s_setprio(0);                                              \
    TAIL_CODE;                                                                  \
    __builtin_amdgcn_s_barrier();                                               \
    asm volatile("" ::: "memory");                                              \
  }

  // ---- prologue: tile0 (k0,k1) -> buf0, tile1 k0 -> buf1  (12 loads)
  STG(Bb, 0,   32768);   // B0K0
  STG(Ab, 0,   0);       // A0K0
  STG(Bb, 32,  49152);   // B0K1
  STG(Ab, 32,  16384);   // A0K1
  STG(Bb, 64,  98304);   // B1K0 (tile1 k0)
  STG(Ab, 64,  65536);   // A1K0
  WAITV(8)               // retire tile0.k0 group
  __builtin_amdgcn_s_barrier();
  asm volatile("" ::: "memory");

  // ---- iter it: compute tiles 2it (buf0, p1-p4) and 2it+1 (buf1, p5-p8).
  // stages: p1 B1K1(t1) p2 A1K1(t1) p3 B0K0(t2) p4 A0K0(t2)
  //         p5 B0K1(t2) p6 A0K1(t2) p7 B1K0(t3) p8 A1K0(t3)
  // waits vmcnt(8) at p2/p4/p6/p8 tails: each retires a 2-stage group issued
  // >=4 phases earlier. Outstanding oscillates 8..12, never drains.
#define ITER(T1, T2, T3, W2, W4, W6, G)                                         \
  LOADB(32768)                                                                  \
  PH(0, 0, STG(Bb, (T1) * 64 + 32, 114688), {})                                 \
  PH(0, 1, STG(Ab, (T1) * 64 + 32, 81920), WAITV(W2))                           \
  LOADB(49152)                                                                  \
  PH(16384, 0, { if (G) STG(Bb, (T2) * 64, 32768) }, {})                        \
  PH(16384, 1, { if (G) STG(Ab, (T2) * 64, 0) }, WAITV(W4))                     \
  LOADB(98304)                                                                  \
  PH(65536, 0, { if (G) STG(Bb, (T2) * 64 + 32, 49152) }, {})                   \
  PH(65536, 1, { if (G) STG(Ab, (T2) * 64 + 32, 16384) }, WAITV(W6))            \
  LOADB(114688)                                                                 \
  PH(81920, 0, { if (G) STG(Bb, (T3) * 64, 98304) }, {})                        \
  PH(81920, 1, { if (G) STG(Ab, (T3) * 64, 65536) }, WAITV(0))

  for (int it = 0; it < 7; ++it) {
    LOADB(32768)
    PH(0, 0, STG(Bb, (2 * it + 1) * 64 + 32, 114688), {})
    PH(0, 1, STG(Ab, (2 * it + 1) * 64 + 32, 81920), WAITV(8))
    LOADB(49152)
    PH(16384, 0, STG(Bb, (2 * it + 2) * 64, 32768), {})
    PH(16384, 1, STG(Ab, (2 * it + 2) * 64, 0), WAITV(8))
    LOADB(98304)
    PH(65536, 0, STG(Bb, (2 * it + 2) * 64 + 32, 49152), {})
    PH(65536, 1, STG(Ab, (2 * it + 2) * 64 + 32, 16384), WAITV(8))
    LOADB(114688)
    PH(81920, 0, STG(Bb, (2 * it + 3) * 64, 98304), {})
    PH(81920, 1, STG(Ab, (2 * it + 3) * 64, 65536), WAITV(8))
  }
  // ---- final iter (tiles 14,15): only p1/p2 stage (tile15.k1); waits 8,4,0
  LOADB(32768)
  PH(0, 0, STG(Bb, 15 * 64 + 32, 114688), {})
  PH(0, 1, STG(Ab, 15 * 64 + 32, 81920), WAITV(8))
  LOADB(49152)
  PH(16384, 0, {}, {})
  PH(16384, 1, {}, WAITV(4))
  LOADB(98304)
  PH(65536, 0, {}, {})
  PH(65536, 1, {}, WAITV(0))
  LOADB(114688)
  PH(81920, 0, {}, {})
  PH(81920, 1, {}, {})

#undef ITER
#undef PH
#undef WAITV
#undef LOADB
#undef STG
#undef STG2

  // ---- epilogue: swapped-operand layout -> lane ℓ reg t holds
  // C[row = wr*128+M*16+(ℓ&15)][col = wc*64+n*16+(ℓ>>4)*4+t]: direct 8B stores.
  const float* bias = (tn < 4) ? (bq + tn * 256) : (bkv + (tn - 4) * 256);
  float4 bv[4];
#pragma unroll
  for (int n = 0; n < 4; ++n)
    bv[n] = *(const float4*)(bias + wc * 64 + n * 16 + hi * 4);

#pragma unroll
  for (int M = 0; M < 8; ++M) {
    size_t row = (size_t)tm * 256 + wr * 128 + M * 16 + lr;
    ushort* cp = C + row * NN + tn * 256 + wc * 64 + hi * 4;
#pragma unroll
    for (int n = 0; n < 4; ++n) {
      unsigned p0 = (unsigned)f2bf(acc[M][n][0] + bv[n].x) |
                    ((unsigned)f2bf(acc[M][n][1] + bv[n].y) << 16);
      unsigned p1 = (unsigned)f2bf(acc[M][n][2] + bv[n].z) |
                    ((unsigned)f2bf(acc[M][n][3] + bv[n].w) << 16);
      uint2 st; st.x = p0; st.y = p1;
      *(uint2*)(cp + n * 16) = st;
    }
  }
}

// ------------------------------------------------- global attention, split-K flash
#define GCH 8
#define GCS (SS / GCH)  // 512

__global__ __launch_bounds__(512) void gattn_part_k(const ushort* __restrict__ QK,
                                                    const float* __restrict__ mask,
                                                    float* __restrict__ P) {
  const int bh = blockIdx.x >> 3, c = blockIdx.x & 7;
  const int b = bh >> 4, h = bh & 15;
  const int tid = threadIdx.x, w = tid >> 6, lane = tid & 63;
  __shared__ float sc[GCS];
  __shared__ float red[8];
  __shared__ float vacc[8][64];

  const float gq = bf2f(QK[(size_t)b * SS * NN + h * HDIM + lane]);  // Q row s=0
  const int s0 = c * GCS;
  float mx = -1e30f;
  for (int s = w; s < GCS; s += 8) {
    float kv = bf2f(QK[((size_t)b * SS + s0 + s) * NN + HID + h * HDIM + lane]);
    float p = gq * kv;
#pragma unroll
    for (int o = 32; o; o >>= 1) p += __shfl_xor(p, o, 64);
    p = p * 0.125f + mask[b * SS + s0 + s];
    if (lane == 0) sc[s] = p;
    mx = fmaxf(mx, p);
  }
  if (lane == 0) red[w] = mx;
  __syncthreads();
  float bm = -1e30f;
#pragma unroll
  for (int i = 0; i < 8; ++i) bm = fmaxf(bm, red[i]);
  __syncthreads();
  float ls = 0.f;
  for (int s = tid; s < GCS; s += 512) {
    float e = __expf(sc[s] - bm);
    sc[s] = e;
    ls += e;
  }
#pragma unroll
  for (int o = 32; o; o >>= 1) ls += __shfl_xor(ls, o, 64);
  if (lane == 0) red[w] = ls;
  __syncthreads();
  float tot = 0.f;
#pragma unroll
  for (int i = 0; i < 8; ++i) tot += red[i];

  float a = 0.f;
  for (int s = w; s < GCS; s += 8)
    a += sc[s] * bf2f(QK[((size_t)b * SS + s0 + s) * NN + HID + h * HDIM + lane]);
  vacc[w][lane] = a;
  __syncthreads();
  if (w == 0) {
    float v = 0.f;
#pragma unroll
    for (int i = 0; i < 8; ++i) v += vacc[i][lane];
    P[1024 + (bh * 8 + c) * 64 + lane] = v;
    if (lane == 0) {
      P[bh * 8 + c] = bm;
      P[512 + bh * 8 + c] = tot;
    }
  }
}

__global__ __launch_bounds__(64) void gattn_comb_k(const float* __restrict__ P,
                                                   float* __restrict__ ctx,
                                                   float* __restrict__ gvec) {
  const int bh = blockIdx.x, b = bh >> 4, h = bh & 15;
  const int lane = threadIdx.x;
  float pm[8];
  float m = -1e30f;
#pragma unroll
  for (int c = 0; c < 8; ++c) { pm[c] = P[bh * 8 + c]; m = fmaxf(m, pm[c]); }
  float tot = 0.f, g = 0.f;
#pragma unroll
  for (int c = 0; c < 8; ++c) {
    float e = __expf(pm[c] - m);
    tot += P[512 + bh * 8 + c] * e;
    g += P[1024 + (bh * 8 + c) * 64 + lane] * e;
  }
  g /= tot;
  gvec[b * HID + h * HDIM + lane] = g;
  ctx[(size_t)b * SS * HID + h * HDIM + lane] = g;
}

// ------------------------------------------------- local attention (4 keys/pos)
__device__ __forceinline__ void unpack16(const ushort* __restrict__ p, float* f) {
  uint4 v0 = *(const uint4*)p;
  uint4 v1 = *(const uint4*)(p + 8);
  unsigned u[8] = {v0.x, v0.y, v0.z, v0.w, v1.x, v1.y, v1.z, v1.w};
#pragma unroll
  for (int i = 0; i < 8; ++i) {
    f[2*i]   = __uint_as_float(u[i] << 16);
    f[2*i+1] = __uint_as_float(u[i] & 0xffff0000u);
  }
}

__global__ __launch_bounds__(256) void local_attn_k(const ushort* __restrict__ QK,
                                                    const float* __restrict__ gvec,
                                                    float* __restrict__ out) {
  const int blk = blockIdx.x;
  const int b = blk >> 10;
  const int s = 1 + ((blk & 1023) << 2) + (int)(threadIdx.x >> 6);
  if (s >= SS) return;
  const int lane = threadIdx.x & 63;
  const int g = lane >> 2, j = lane & 3;
  const int db = g*HDIM + j*16;

  const size_t base = ((size_t)b*SS + s) * NN;
  const ushort* qp  = QK + base + db;
  const ushort* ksp = QK + base + HID + db;
  const ushort* kpp = QK + base - NN + HID + db;
  const int sn = (s == SS-1) ? 0 : s + 1;
  const ushort* knp = QK + ((size_t)b*SS + sn)*NN + HID + db;
  const float*  gvp = gvec + b*HID + db;

  float q[16], ks[16], kp[16], kn[16], gv[16];
  unpack16(qp, q); unpack16(ksp, ks); unpack16(kpp, kp); unpack16(knp, kn);
#pragma unroll
  for (int t = 0; t < 16; t += 4) *(float4*)(gv + t) = *(const float4*)(gvp + t);

  float d0=0.f, d1=0.f, d2=0.f, d3=0.f;
#pragma unroll
  for (int t = 0; t < 16; ++t) {
    d0 += q[t]*ks[t]; d1 += q[t]*gv[t]; d2 += q[t]*kp[t]; d3 += q[t]*kn[t];
  }
  d0 += __shfl_xor(d0, 1, 64); d0 += __shfl_xor(d0, 2, 64);
  d1 += __shfl_xor(d1, 1, 64); d1 += __shfl_xor(d1, 2, 64);
  d2 += __shfl_xor(d2, 1, 64); d2 += __shfl_xor(d2, 2, 64);
  d3 += __shfl_xor(d3, 1, 64); d3 += __shfl_xor(d3, 2, 64);

  float s0 = d0*0.125f, s1 = d1*0.125f, s2 = d2*0.125f, s3 = d3*0.125f;
  float m = fmaxf(fmaxf(s0, s1), fmaxf(s2, s3));
  float e0 = __expf(s0 - m), e1 = __expf(s1 - m), e2 = __expf(s2 - m), e3 = __expf(s3 - m);
  float inv = 1.f / (e0 + e1 + e2 + e3);
  float a0 = e0*inv, a1 = e1*inv, a2 = e2*inv, a3 = e3*inv;

  float o[16];
#pragma unroll
  for (int t = 0; t < 16; ++t) o[t] = a0*ks[t] + a1*gv[t] + a2*kp[t] + a3*kn[t];
  float* cp = out + ((size_t)b*SS + s)*HID + db;
#pragma unroll
  for (int t = 0; t < 16; t += 4) *(float4*)(cp + t) = *(const float4*)(o + t);

  if (j == 0) {
    float4 av; av.x = a0; av.y = a1; av.z = a2; av.w = a3;
    *(float4*)(out + (size_t)BB*SS*HID + (((size_t)b*NHEADS + g)*(SS-1) + (s-1))*4) = av;
  }
}

// ---------------------------------------------------------------------- launch
extern "C" void kernel_launch(void* const* d_in, const int* in_sizes, int n_in,
                              void* d_out, int out_size, void* d_ws, size_t ws_size,
                              hipStream_t stream) {
  const float* hs   = (const float*)d_in[0];
  const float* mask = (const float*)d_in[1];
  const float* Wq   = (const float*)d_in[2];
  const float* bq   = (const float*)d_in[3];
  const float* Wkv  = (const float*)d_in[4];
  const float* bkv  = (const float*)d_in[5];
  float* out = (float*)d_out;

  char* ws = (char*)d_ws;
  ushort* hsb  = (ushort*)ws;                                   // 32 MB
  ushort* Bt   = (ushort*)(ws + 33554432);                      // 4 MB
  ushort* QK   = (ushort*)(ws + 33554432 + 4194304);            // 64 MB
  float*  gvec = (float*)(ws + 33554432 + 4194304 + 67108864);  // 16 KB
  float*  P    = (float*)(ws + 33554432 + 4194304 + 67108864 + 16384);  // ~140 KB

  cast_hs_k<<<MM*KK/(256*8), 256, 0, stream>>>(hs, hsb);
  wcast_k<<<dim3(KK/32, NN/32), dim3(32, 8), 0, stream>>>(Wq, Wkv, Bt);
  gemm_k<<<dim3((MM/256)*(NN/256)), dim3(512), 131072, stream>>>(hsb, Bt, bq, bkv, QK);
  gattn_part_k<<<BB*NHEADS*GCH, 512, 0, stream>>>(QK, mask, P);
  gattn_comb_k<<<BB*NHEADS, 64, 0, stream>>>(P, out, gvec);
  local_attn_k<<<BB*1024, 256, 0, stream>>>(QK, gvec, out);
}

// Round 5
// 176.101 us; speedup vs baseline: 1.0076x; 1.0076x over previous
//
#include <hip/hip_runtime.h>
#include <hip/hip_bf16.h>

#define NHEADS 16
#define HDIM   64
#define HID    1024
#define BB     4
#define SS     4096
#define MM     (BB*SS)      // 16384 rows
#define KK     HID          // 1024
#define NN     (2*HID)      // 2048 cols (Q | K)

using short8 = __attribute__((ext_vector_type(8))) short;
using f32x4  = __attribute__((ext_vector_type(4))) float;

__device__ __forceinline__ float bf2f(ushort u) {
  return __uint_as_float(((unsigned)u) << 16);
}
__device__ __forceinline__ ushort f2bf(float f) {
  unsigned u = __float_as_uint(f);
  unsigned r = (u + 0x7fffu + ((u >> 16) & 1u)) >> 16;  // RNE
  return (ushort)r;
}

__device__ __forceinline__ void gload16(const void* g, void* l) {
  __builtin_amdgcn_global_load_lds(
      (const __attribute__((address_space(1))) void*)g,
      (__attribute__((address_space(3))) void*)l, 16, 0, 0);
}

// ---------------------------------------------------------------- cast hs->bf16
__global__ __launch_bounds__(256) void cast_hs_k(const float* __restrict__ in,
                                                 ushort* __restrict__ out) {
  size_t i = ((size_t)blockIdx.x * 256 + threadIdx.x) * 8;
  float4 a = *(const float4*)(in + i);
  float4 b = *(const float4*)(in + i + 4);
  ushort r[8];
  r[0]=f2bf(a.x); r[1]=f2bf(a.y); r[2]=f2bf(a.z); r[3]=f2bf(a.w);
  r[4]=f2bf(b.x); r[5]=f2bf(b.y); r[6]=f2bf(b.z); r[7]=f2bf(b.w);
  *(uint4*)(out + i) = *(const uint4*)r;
}

// ------------------------------------------- W (K,N) -> Bt (N,K) bf16, Wq|Wkv fused
__global__ __launch_bounds__(256) void wcast_k(const float* __restrict__ Wq,
                                               const float* __restrict__ Wkv,
                                               ushort* __restrict__ Bt) {
  __shared__ float tile[32][33];
  int k0 = blockIdx.x * 32, n0 = blockIdx.y * 32;
  int tx = threadIdx.x, ty = threadIdx.y;
  const float* src = (n0 < HID) ? Wq : Wkv;
  int nc = (n0 < HID) ? n0 : n0 - HID;
#pragma unroll
  for (int j = 0; j < 4; ++j)
    tile[ty + 8*j][tx] = src[(size_t)(k0 + ty + 8*j) * HID + nc + tx];
  __syncthreads();
#pragma unroll
  for (int j = 0; j < 4; ++j)
    Bt[(size_t)(n0 + ty + 8*j) * KK + k0 + tx] = f2bf(tile[tx][ty + 8*j]);
}

// ---------------------------------------------------------------- fused QK GEMM
// 256x256 tile, BK=64, 8 waves (2Mx4N), 512 threads, 128KB LDS double-buffer.
// 8-phase counted-vmcnt schedule with K-split staging (verified ledger: every
// staged slice has 4-5 phases issue-to-wait distance; outstanding 8..12).
// R5 changes vs R4 (scheduling only, semantics identical):
//  * sched_barrier(0) after the pre-MFMA s_barrier  [rule 18: stop hipcc
//    hoisting register-only MFMAs above the barrier]
//  * #pragma unroll 1 on the main loop [keep body I$-resident instead of
//    ~28KB straight-line code]
// LDS byte map: A0K0=0 A0K1=16384 B0K0=32768 B0K1=49152
//               A1K0=65536 A1K1=81920 B1K0=98304 B1K1=114688
__global__ __launch_bounds__(512, 2) void gemm_k(const ushort* __restrict__ A,
                                                 const ushort* __restrict__ Bt,
                                                 const float* __restrict__ bq,
                                                 const float* __restrict__ bkv,
                                                 ushort* __restrict__ C) {
  extern __shared__ char lds_c[];
  const int tid = threadIdx.x;
  const int bid = blockIdx.x;
  const int wg = (bid & 7) * 64 + (bid >> 3);   // XCD swizzle (512 % 8 == 0)
  const int tm = wg >> 3, tn = wg & 7;
  const int w = tid >> 6, lane = tid & 63;
  const int wr = w >> 2, wc = w & 3;
  const int lr = lane & 15, hi = lane >> 4;

  const ushort* Ab = A  + (size_t)tm * 256 * KK;
  const ushort* Bb = Bt + (size_t)tn * 256 * KK;

  // staging: slice = 256 rows x 32 cols; thread t -> row t>>2 (+128 for j=1),
  // LDS chunk t&3; global chunk = (t&3) ^ ((t>>3)&3)  (involution pre-swizzle)
  const int d0 = tid * 16;                 // LDS byte offset, j=0
  const int gch = (tid & 3) ^ ((tid >> 3) & 3);
  const size_t soff0 = (size_t)(tid >> 2) * KK + gch * 8;
  const size_t soff1 = soff0 + (size_t)128 * KK;

  // fragment-read swizzle: chunk' = hi ^ ((row>>1)&3); (row>>1)&3 == (lr>>1)&3
  const int swz = (hi ^ ((lr >> 1) & 3)) << 4;
  const int arow = (wr * 128 + lr) * 64 + swz;   // + MH*4096 + m*1024
  const int brow = (wc * 64 + lr) * 64 + swz;    // + n*1024

  f32x4 acc[8][4];
#pragma unroll
  for (int M = 0; M < 8; ++M)
#pragma unroll
    for (int n = 0; n < 4; ++n) acc[M][n] = (f32x4){0.f, 0.f, 0.f, 0.f};
  short8 bfrag[4];

#define STG(PANEL, KOFF, DSTB)                                                  \
  {                                                                             \
    const ushort* g_ = (PANEL) + (KOFF);                                        \
    gload16(g_ + soff0, lds_c + (DSTB) + d0);                                   \
    gload16(g_ + soff1, lds_c + (DSTB) + 8192 + d0);                            \
  }

#define LOADB(BBASE)                                                            \
  _Pragma("unroll") for (int n = 0; n < 4; ++n)                                 \
    bfrag[n] = *(const short8*)(lds_c + (BBASE) + n * 1024 + brow);

#define WAITV(N)                                                                \
  { asm volatile("s_waitcnt vmcnt(" #N ")" ::: "memory");                       \
    __builtin_amdgcn_sched_barrier(0); }

#define PH(ABASE, MH, STAGE_CODE, TAIL_CODE)                                    \
  {                                                                             \
    short8 afrag[4];                                                            \
    _Pragma("unroll") for (int m = 0; m < 4; ++m)                               \
      afrag[m] = *(const short8*)(lds_c + (ABASE) + (MH) * 4096 +               \
                                  m * 1024 + arow);                             \
    STAGE_CODE;                                                                 \
    __builtin_amdgcn_s_barrier();                                               \
    __builtin_amdgcn_sched_barrier(0); /* rule 18: pin MFMA below barrier */    \
    __builtin_amdgcn_s_setprio(1);                                              \
    _Pragma("unroll") for (int m = 0; m < 4; ++m)                               \
      _Pragma("unroll") for (int n = 0; n < 4; ++n)                             \
        acc[(MH) * 4 + m][n] = __builtin_amdgcn_mfma_f32_16x16x32_bf16(         \
            bfrag[n], afrag[m], acc[(MH) * 4 + m][n], 0, 0, 0);                 \
    __builtin_amdgcn_s_setprio(0);                                              \
    TAIL_CODE;                                                                  \
    __builtin_amdgcn_s_barrier();                                               \
    asm volatile("" ::: "memory");                                              \
  }

  // ---- prologue: tile0 (k0,k1) -> buf0, tile1 k0 -> buf1  (12 loads)
  STG(Bb, 0,   32768);   // B0K0
  STG(Ab, 0,   0);       // A0K0
  STG(Bb, 32,  49152);   // B0K1
  STG(Ab, 32,  16384);   // A0K1
  STG(Bb, 64,  98304);   // B1K0 (tile1 k0)
  STG(Ab, 64,  65536);   // A1K0
  WAITV(8)               // retire tile0.k0 group
  __builtin_amdgcn_s_barrier();
  asm volatile("" ::: "memory");

  // ---- iter it: compute tiles 2it (buf0, p1-p4) and 2it+1 (buf1, p5-p8).
  // stages: p1 B1K1(t1) p2 A1K1(t1) p3 B0K0(t2) p4 A0K0(t2)
  //         p5 B0K1(t2) p6 A0K1(t2) p7 B1K0(t3) p8 A1K0(t3)
  // waits vmcnt(8) at p2/p4/p6/p8 tails: each retires a 2-stage group issued
  // 4-5 phases earlier. Outstanding oscillates 8..12, never drains.
#pragma unroll 1
  for (int it = 0; it < 7; ++it) {
    LOADB(32768)
    PH(0, 0, STG(Bb, (2 * it + 1) * 64 + 32, 114688), {})
    PH(0, 1, STG(Ab, (2 * it + 1) * 64 + 32, 81920), WAITV(8))
    LOADB(49152)
    PH(16384, 0, STG(Bb, (2 * it + 2) * 64, 32768), {})
    PH(16384, 1, STG(Ab, (2 * it + 2) * 64, 0), WAITV(8))
    LOADB(98304)
    PH(65536, 0, STG(Bb, (2 * it + 2) * 64 + 32, 49152), {})
    PH(65536, 1, STG(Ab, (2 * it + 2) * 64 + 32, 16384), WAITV(8))
    LOADB(114688)
    PH(81920, 0, STG(Bb, (2 * it + 3) * 64, 98304), {})
    PH(81920, 1, STG(Ab, (2 * it + 3) * 64, 65536), WAITV(8))
  }
  // ---- final iter (tiles 14,15): only p1/p2 stage (tile15.k1); waits 8,4,0
  LOADB(32768)
  PH(0, 0, STG(Bb, 15 * 64 + 32, 114688), {})
  PH(0, 1, STG(Ab, 15 * 64 + 32, 81920), WAITV(8))
  LOADB(49152)
  PH(16384, 0, {}, {})
  PH(16384, 1, {}, WAITV(4))
  LOADB(98304)
  PH(65536, 0, {}, {})
  PH(65536, 1, {}, WAITV(0))
  LOADB(114688)
  PH(81920, 0, {}, {})
  PH(81920, 1, {}, {})

#undef PH
#undef WAITV
#undef LOADB
#undef STG

  // ---- epilogue: swapped-operand layout -> lane ℓ reg t holds
  // C[row = wr*128+M*16+(ℓ&15)][col = wc*64+n*16+(ℓ>>4)*4+t]: direct 8B stores.
  const float* bias = (tn < 4) ? (bq + tn * 256) : (bkv + (tn - 4) * 256);
  float4 bv[4];
#pragma unroll
  for (int n = 0; n < 4; ++n)
    bv[n] = *(const float4*)(bias + wc * 64 + n * 16 + hi * 4);

#pragma unroll
  for (int M = 0; M < 8; ++M) {
    size_t row = (size_t)tm * 256 + wr * 128 + M * 16 + lr;
    ushort* cp = C + row * NN + tn * 256 + wc * 64 + hi * 4;
#pragma unroll
    for (int n = 0; n < 4; ++n) {
      unsigned p0 = (unsigned)f2bf(acc[M][n][0] + bv[n].x) |
                    ((unsigned)f2bf(acc[M][n][1] + bv[n].y) << 16);
      unsigned p1 = (unsigned)f2bf(acc[M][n][2] + bv[n].z) |
                    ((unsigned)f2bf(acc[M][n][3] + bv[n].w) << 16);
      uint2 st; st.x = p0; st.y = p1;
      *(uint2*)(cp + n * 16) = st;
    }
  }
}

// ------------------------------------------------- global attention, split-K flash
#define GCH 8
#define GCS (SS / GCH)  // 512

__global__ __launch_bounds__(512) void gattn_part_k(const ushort* __restrict__ QK,
                                                    const float* __restrict__ mask,
                                                    float* __restrict__ P) {
  const int bh = blockIdx.x >> 3, c = blockIdx.x & 7;
  const int b = bh >> 4, h = bh & 15;
  const int tid = threadIdx.x, w = tid >> 6, lane = tid & 63;
  __shared__ float sc[GCS];
  __shared__ float red[8];
  __shared__ float vacc[8][64];

  const float gq = bf2f(QK[(size_t)b * SS * NN + h * HDIM + lane]);  // Q row s=0
  const int s0 = c * GCS;
  float mx = -1e30f;
  for (int s = w; s < GCS; s += 8) {
    float kv = bf2f(QK[((size_t)b * SS + s0 + s) * NN + HID + h * HDIM + lane]);
    float p = gq * kv;
#pragma unroll
    for (int o = 32; o; o >>= 1) p += __shfl_xor(p, o, 64);
    p = p * 0.125f + mask[b * SS + s0 + s];
    if (lane == 0) sc[s] = p;
    mx = fmaxf(mx, p);
  }
  if (lane == 0) red[w] = mx;
  __syncthreads();
  float bm = -1e30f;
#pragma unroll
  for (int i = 0; i < 8; ++i) bm = fmaxf(bm, red[i]);
  __syncthreads();
  float ls = 0.f;
  for (int s = tid; s < GCS; s += 512) {
    float e = __expf(sc[s] - bm);
    sc[s] = e;
    ls += e;
  }
#pragma unroll
  for (int o = 32; o; o >>= 1) ls += __shfl_xor(ls, o, 64);
  if (lane == 0) red[w] = ls;
  __syncthreads();
  float tot = 0.f;
#pragma unroll
  for (int i = 0; i < 8; ++i) tot += red[i];

  float a = 0.f;
  for (int s = w; s < GCS; s += 8)
    a += sc[s] * bf2f(QK[((size_t)b * SS + s0 + s) * NN + HID + h * HDIM + lane]);
  vacc[w][lane] = a;
  __syncthreads();
  if (w == 0) {
    float v = 0.f;
#pragma unroll
    for (int i = 0; i < 8; ++i) v += vacc[i][lane];
    P[1024 + (bh * 8 + c) * 64 + lane] = v;
    if (lane == 0) {
      P[bh * 8 + c] = bm;
      P[512 + bh * 8 + c] = tot;
    }
  }
}

__global__ __launch_bounds__(64) void gattn_comb_k(const float* __restrict__ P,
                                                   float* __restrict__ ctx,
                                                   float* __restrict__ gvec) {
  const int bh = blockIdx.x, b = bh >> 4, h = bh & 15;
  const int lane = threadIdx.x;
  float pm[8];
  float m = -1e30f;
#pragma unroll
  for (int c = 0; c < 8; ++c) { pm[c] = P[bh * 8 + c]; m = fmaxf(m, pm[c]); }
  float tot = 0.f, g = 0.f;
#pragma unroll
  for (int c = 0; c < 8; ++c) {
    float e = __expf(pm[c] - m);
    tot += P[512 + bh * 8 + c] * e;
    g += P[1024 + (bh * 8 + c) * 64 + lane] * e;
  }
  g /= tot;
  gvec[b * HID + h * HDIM + lane] = g;
  ctx[(size_t)b * SS * HID + h * HDIM + lane] = g;
}

// ------------------------------------------------- local attention (4 keys/pos)
__device__ __forceinline__ void unpack16(const ushort* __restrict__ p, float* f) {
  uint4 v0 = *(const uint4*)p;
  uint4 v1 = *(const uint4*)(p + 8);
  unsigned u[8] = {v0.x, v0.y, v0.z, v0.w, v1.x, v1.y, v1.z, v1.w};
#pragma unroll
  for (int i = 0; i < 8; ++i) {
    f[2*i]   = __uint_as_float(u[i] << 16);
    f[2*i+1] = __uint_as_float(u[i] & 0xffff0000u);
  }
}

__global__ __launch_bounds__(256) void local_attn_k(const ushort* __restrict__ QK,
                                                    const float* __restrict__ gvec,
                                                    float* __restrict__ out) {
  const int blk = blockIdx.x;
  const int b = blk >> 10;
  const int s = 1 + ((blk & 1023) << 2) + (int)(threadIdx.x >> 6);
  if (s >= SS) return;
  const int lane = threadIdx.x & 63;
  const int g = lane >> 2, j = lane & 3;
  const int db = g*HDIM + j*16;

  const size_t base = ((size_t)b*SS + s) * NN;
  const ushort* qp  = QK + base + db;
  const ushort* ksp = QK + base + HID + db;
  const ushort* kpp = QK + base - NN + HID + db;
  const int sn = (s == SS-1) ? 0 : s + 1;
  const ushort* knp = QK + ((size_t)b*SS + sn)*NN + HID + db;
  const float*  gvp = gvec + b*HID + db;

  float q[16], ks[16], kp[16], kn[16], gv[16];
  unpack16(qp, q); unpack16(ksp, ks); unpack16(kpp, kp); unpack16(knp, kn);
#pragma unroll
  for (int t = 0; t < 16; t += 4) *(float4*)(gv + t) = *(const float4*)(gvp + t);

  float d0=0.f, d1=0.f, d2=0.f, d3=0.f;
#pragma unroll
  for (int t = 0; t < 16; ++t) {
    d0 += q[t]*ks[t]; d1 += q[t]*gv[t]; d2 += q[t]*kp[t]; d3 += q[t]*kn[t];
  }
  d0 += __shfl_xor(d0, 1, 64); d0 += __shfl_xor(d0, 2, 64);
  d1 += __shfl_xor(d1, 1, 64); d1 += __shfl_xor(d1, 2, 64);
  d2 += __shfl_xor(d2, 1, 64); d2 += __shfl_xor(d2, 2, 64);
  d3 += __shfl_xor(d3, 1, 64); d3 += __shfl_xor(d3, 2, 64);

  float s0 = d0*0.125f, s1 = d1*0.125f, s2 = d2*0.125f, s3 = d3*0.125f;
  float m = fmaxf(fmaxf(s0, s1), fmaxf(s2, s3));
  float e0 = __expf(s0 - m), e1 = __expf(s1 - m), e2 = __expf(s2 - m), e3 = __expf(s3 - m);
  float inv = 1.f / (e0 + e1 + e2 + e3);
  float a0 = e0*inv, a1 = e1*inv, a2 = e2*inv, a3 = e3*inv;

  float o[16];
#pragma unroll
  for (int t = 0; t < 16; ++t) o[t] = a0*ks[t] + a1*gv[t] + a2*kp[t] + a3*kn[t];
  float* cp = out + ((size_t)b*SS + s)*HID + db;
#pragma unroll
  for (int t = 0; t < 16; t += 4) *(float4*)(cp + t) = *(const float4*)(o + t);

  if (j == 0) {
    float4 av; av.x = a0; av.y = a1; av.z = a2; av.w = a3;
    *(float4*)(out + (size_t)BB*SS*HID + (((size_t)b*NHEADS + g)*(SS-1) + (s-1))*4) = av;
  }
}

// ---------------------------------------------------------------------- launch
extern "C" void kernel_launch(void* const* d_in, const int* in_sizes, int n_in,
                              void* d_out, int out_size, void* d_ws, size_t ws_size,
                              hipStream_t stream) {
  const float* hs   = (const float*)d_in[0];
  const float* mask = (const float*)d_in[1];
  const float* Wq   = (const float*)d_in[2];
  const float* bq   = (const float*)d_in[3];
  const float* Wkv  = (const float*)d_in[4];
  const float* bkv  = (const float*)d_in[5];
  float* out = (float*)d_out;

  char* ws = (char*)d_ws;
  ushort* hsb  = (ushort*)ws;                                   // 32 MB
  ushort* Bt   = (ushort*)(ws + 33554432);                      // 4 MB
  ushort* QK   = (ushort*)(ws + 33554432 + 4194304);            // 64 MB
  float*  gvec = (float*)(ws + 33554432 + 4194304 + 67108864);  // 16 KB
  float*  P    = (float*)(ws + 33554432 + 4194304 + 67108864 + 16384);  // ~140 KB

  cast_hs_k<<<MM*KK/(256*8), 256, 0, stream>>>(hs, hsb);
  wcast_k<<<dim3(KK/32, NN/32), dim3(32, 8), 0, stream>>>(Wq, Wkv, Bt);
  gemm_k<<<dim3((MM/256)*(NN/256)), dim3(512), 131072, stream>>>(hsb, Bt, bq, bkv, QK);
  gattn_part_k<<<BB*NHEADS*GCH, 512, 0, stream>>>(QK, mask, P);
  gattn_comb_k<<<BB*NHEADS, 64, 0, stream>>>(P, out, gvec);
  local_attn_k<<<BB*1024, 256, 0, stream>>>(QK, gvec, out);
}